// Round 6
// baseline (403.534 us; speedup 1.0000x reference)
//
#include <hip/hip_runtime.h>
#include <hip/hip_bf16.h>
#include <math.h>

#define BB 8
#define LL 4096
#define DD 768
#define NN 16
#define RR 8
#define MROWS (BB*LL)       // 32768 rows
#define KAUG 800            // 768 (x) + 16 (hs) + 16 (zero pad)
#define CCH 64              // chunk length for scan
#define NCH (LL/CCH)        // 64 chunks per batch

typedef unsigned int u32;
typedef unsigned short u16;
typedef __attribute__((ext_vector_type(8))) short short8;
typedef __attribute__((ext_vector_type(4))) float f32x4;
typedef __attribute__((ext_vector_type(4))) u32 u32x4;

__device__ __forceinline__ u16 f2bf(float f) {
  u32 u = __float_as_uint(f);
  u32 r = (u + 0x7fffu + ((u >> 16) & 1u)) >> 16;  // RNE
  return (u16)r;
}

__device__ __forceinline__ u32 pk2bf(float a, float b) {
  __hip_bfloat162 h = __float22bfloat162_rn(make_float2(a, b));
  return *reinterpret_cast<u32*>(&h);
}

__device__ __forceinline__ void gload_lds16(const void* g, void* l) {
  __builtin_amdgcn_global_load_lds(
      (const __attribute__((address_space(1))) u32*)g,
      (__attribute__((address_space(3))) u32*)l, 16, 0, 0);
}

// ---------------- K0a: M = diag(sigmoid(a)) + V U^T ; MC = M^64 ; bsum ----
__global__ void k_prep(const float* __restrict__ a_logit, const float* __restrict__ U,
                       const float* __restrict__ V, const float* __restrict__ b_out,
                       const float* __restrict__ b_skip,
                       float* __restrict__ Mw, float* __restrict__ MCw,
                       float* __restrict__ bsum) {
  __shared__ float cur[256];
  __shared__ float nxt[256];
  int t = threadIdx.x;
  int m = t >> 4, n = t & 15;
  float s = 0.f;
  #pragma unroll
  for (int r = 0; r < RR; r++) s += V[m*RR+r] * U[n*RR+r];
  if (m == n) s += 1.f / (1.f + expf(-a_logit[n]));
  cur[t] = s;
  Mw[t] = s;
  __syncthreads();
  for (int it = 0; it < 6; ++it) {
    float acc = 0.f;
    #pragma unroll
    for (int k = 0; k < 16; k++) acc += cur[m*16+k] * cur[k*16+n];
    nxt[t] = acc;
    __syncthreads();
    cur[t] = nxt[t];
    __syncthreads();
  }
  MCw[t] = cur[t];
  for (int d = t; d < DD; d += 256) bsum[d] = b_out[d] + b_skip[d];
}

// ---------------- K0b: Waug = [W_skip | W_out | 0] bf16 ; WinG = [W_in;W_gate] bf16
__global__ void k_weights(const float* __restrict__ W_skip, const float* __restrict__ W_out,
                          const float* __restrict__ W_in, const float* __restrict__ W_gate,
                          u16* __restrict__ Waug, u16* __restrict__ WinG) {
  int bid = blockIdx.x;
  int t = threadIdx.x;
  if (bid < DD) {
    int d = bid;
    for (int c = t; c < KAUG; c += 256) {
      float v;
      if (c < DD)           v = W_skip[d*DD + c];
      else if (c < DD+NN)   v = W_out[d*NN + (c-DD)];
      else                  v = 0.f;
      Waug[d*KAUG + c] = f2bf(v);
    }
  } else {
    int r = bid - DD;  // 0..31
    const float* Wsrc = (r < NN) ? (W_in + r*DD) : (W_gate + (r-NN)*DD);
    for (int c = t; c < DD; c += 256) WinG[r*DD + c] = f2bf(Wsrc[c]);
  }
}

// ---------------- K2: gu = sigmoid(x@Wg^T+bg)*(x@Wi^T+bi); also fills Xaug bf16
__global__ __launch_bounds__(256) void k_gu(const float* __restrict__ x,
                                            const u16* __restrict__ WinG,
                                            const float* __restrict__ b_in,
                                            const float* __restrict__ b_gate,
                                            float* __restrict__ gu_T,
                                            u16* __restrict__ Xaug) {
  __shared__ u16 At[128*32];
  __shared__ u16 Bt[32*32];
  int tid = threadIdx.x;
  int wave = tid >> 6, lane = tid & 63;
  int rowbase = blockIdx.x * 128;
  int r = tid >> 1, ch = tid & 1;
  const float* xrow = x + (long)(rowbase + r)*DD + ch*16;
  u16* xarow = Xaug + (long)(rowbase + r)*KAUG + ch*16;
  f32x4 acc[2][2] = {};
  for (int it = 0; it < DD/32; ++it) {
    int k0 = it * 32;
    // A: global fp32 -> reg -> bf16 -> LDS  (+ mirror into Xaug)
    {
      const float4* xp = (const float4*)(xrow + k0);
      float4 f0 = xp[0], f1 = xp[1], f2 = xp[2], f3 = xp[3];
      u32x4 lo, hi;
      lo.x = pk2bf(f0.x,f0.y); lo.y = pk2bf(f0.z,f0.w);
      lo.z = pk2bf(f1.x,f1.y); lo.w = pk2bf(f1.z,f1.w);
      hi.x = pk2bf(f2.x,f2.y); hi.y = pk2bf(f2.z,f2.w);
      hi.z = pk2bf(f3.x,f3.y); hi.w = pk2bf(f3.z,f3.w);
      *(u32x4*)(At + r*32 + ch*16)     = lo;
      *(u32x4*)(At + r*32 + ch*16 + 8) = hi;
      *(u32x4*)(xarow + k0)     = lo;
      *(u32x4*)(xarow + k0 + 8) = hi;
    }
    if (tid < 128) {
      int br = tid >> 2, co = tid & 3;
      gload_lds16(WinG + br*DD + k0 + co*8, Bt + tid*8);
    }
    __syncthreads();
    int l15 = lane & 15, lh = lane >> 4;
    short8 a[2], b[2];
    #pragma unroll
    for (int i = 0; i < 2; i++)
      a[i] = *(const short8*)(At + (wave*32 + i*16 + l15)*32 + lh*8);
    #pragma unroll
    for (int j = 0; j < 2; j++)
      b[j] = *(const short8*)(Bt + (j*16 + l15)*32 + lh*8);
    #pragma unroll
    for (int i = 0; i < 2; i++)
      #pragma unroll
      for (int j = 0; j < 2; j++)
        acc[i][j] = __builtin_amdgcn_mfma_f32_16x16x32_bf16(a[i], b[j], acc[i][j], 0, 0, 0);
    __syncthreads();
  }
  // zero pad cols 784..799
  *(u32x4*)(Xaug + (long)(rowbase + r)*KAUG + 784 + ch*8) = (u32x4)0;
  int l15 = lane & 15, lh = lane >> 4;
  float bi = b_in[l15], bg = b_gate[l15];
  #pragma unroll
  for (int i = 0; i < 2; i++) {
    int row0 = rowbase + wave*32 + i*16 + lh*4;   // 4 consecutive rows (same b)
    int b = row0 >> 12;
    int t0 = row0 & 4095;
    float4 o;
    {
      float u0 = acc[i][0][0] + bi, u1 = acc[i][0][1] + bi;
      float u2 = acc[i][0][2] + bi, u3 = acc[i][0][3] + bi;
      float g0 = 1.f/(1.f+__expf(-(acc[i][1][0]+bg)));
      float g1 = 1.f/(1.f+__expf(-(acc[i][1][1]+bg)));
      float g2 = 1.f/(1.f+__expf(-(acc[i][1][2]+bg)));
      float g3 = 1.f/(1.f+__expf(-(acc[i][1][3]+bg)));
      o.x = g0*u0; o.y = g1*u1; o.z = g2*u2; o.w = g3*u3;
    }
    *(float4*)(gu_T + ((long)(b*16 + l15) << 12) + t0) = o;
  }
}

// ---------------- K4: fused scan (local + prefix + final) ; one block per batch
__global__ __launch_bounds__(1024, 4) void k_scan(const float* __restrict__ gu_T,
                                                  const float* __restrict__ Mw,
                                                  const float* __restrict__ MCw,
                                                  u16* __restrict__ Xaug) {
  __shared__ float cend_s[NCH*NN];   // 4 KB
  __shared__ float hst_s[NCH*NN];    // 4 KB
  int b = blockIdx.x;                // batch
  int tid = threadIdx.x;             // 0..1023
  int c = tid >> 4, n = tid & 15;    // chunk, state idx
  float Mcol[16];
  #pragma unroll
  for (int m = 0; m < 16; m++) Mcol[m] = Mw[m*16 + n];
  // preload chunk into regs
  const float4* g4 = (const float4*)(gu_T + ((long)(b*16 + n) << 12) + c*CCH);
  float gv[CCH];
  #pragma unroll
  for (int q = 0; q < CCH/4; q++) {
    float4 v = g4[q];
    gv[q*4+0]=v.x; gv[q*4+1]=v.y; gv[q*4+2]=v.z; gv[q*4+3]=v.w;
  }
  // phase 1: local scan from zero
  float h = 0.f;
  #pragma unroll
  for (int t = 0; t < CCH; t++) {
    float hn = gv[t];
    #pragma unroll
    for (int m = 0; m < 16; m++) hn += __shfl(h, m, 16) * Mcol[m];
    h = hn;
  }
  cend_s[c*16 + n] = h;
  __syncthreads();
  // phase 2: serial prefix over 64 chunk-ends (lanes 0..15 of wave 0)
  if (tid < 16) {
    float MCcol[16];
    #pragma unroll
    for (int m = 0; m < 16; m++) MCcol[m] = MCw[m*16 + tid];
    float hp = 0.f;
    for (int k = 0; k < NCH; k++) {
      hst_s[k*16 + tid] = hp;
      float hn = cend_s[k*16 + tid];
      #pragma unroll
      for (int m = 0; m < 16; m++) hn += __shfl(hp, m, 16) * MCcol[m];
      hp = hn;
    }
  }
  __syncthreads();
  // phase 3: rescan with true start, write hs bf16 into Xaug cols 768..783
  float h2 = hst_s[c*16 + n];
  u16* xa = Xaug + ((long)(b*LL) + c*CCH)*KAUG + DD + n;
  #pragma unroll
  for (int t = 0; t < CCH; t++) {
    float hn = gv[t];
    #pragma unroll
    for (int m = 0; m < 16; m++) hn += __shfl(h2, m, 16) * Mcol[m];
    h2 = hn;
    xa[(long)t*KAUG] = f2bf(h2);
  }
}

// ---------------- K7: y = Xaug @ Waug^T + bsum   (half of N per launch)
__global__ __launch_bounds__(256) void k_out(const u16* __restrict__ Xaug,
                                             const u16* __restrict__ Waug,
                                             const float* __restrict__ bsum,
                                             float* __restrict__ y, int colofs) {
  __shared__ u16 At[128*32];
  __shared__ u16 Bt[128*32];
  int tid = threadIdx.x;
  int wave = tid >> 6, lane = tid & 63;
  int wm = wave >> 1, wn = wave & 1;
  int rowbase = blockIdx.x * 128;
  int colbase = (blockIdx.y + colofs) * 128;
  f32x4 acc[4][4] = {};
  for (int it = 0; it < KAUG/32; ++it) {
    int k0 = it * 32;
    #pragma unroll
    for (int p = 0; p < 2; p++) {
      int cc = tid + p*256;
      int r = cc >> 2, co = cc & 3;
      gload_lds16(Xaug + (long)(rowbase + r)*KAUG + k0 + co*8, At + cc*8);
      gload_lds16(Waug + (long)(colbase + r)*KAUG + k0 + co*8, Bt + cc*8);
    }
    __syncthreads();
    int l15 = lane & 15, lh = lane >> 4;
    short8 a[4], b[4];
    #pragma unroll
    for (int i = 0; i < 4; i++)
      a[i] = *(const short8*)(At + (wm*64 + i*16 + l15)*32 + lh*8);
    #pragma unroll
    for (int j = 0; j < 4; j++)
      b[j] = *(const short8*)(Bt + (wn*64 + j*16 + l15)*32 + lh*8);
    #pragma unroll
    for (int i = 0; i < 4; i++)
      #pragma unroll
      for (int j = 0; j < 4; j++)
        acc[i][j] = __builtin_amdgcn_mfma_f32_16x16x32_bf16(a[i], b[j], acc[i][j], 0, 0, 0);
    __syncthreads();
  }
  int l15 = lane & 15, lh = lane >> 4;
  #pragma unroll
  for (int j = 0; j < 4; j++) {
    int col = colbase + wn*64 + j*16 + l15;
    float bs = bsum[col];
    #pragma unroll
    for (int i = 0; i < 4; i++) {
      int row0 = rowbase + wm*64 + i*16 + lh*4;
      #pragma unroll
      for (int rr = 0; rr < 4; rr++)
        y[(long)(row0 + rr)*DD + col] = acc[i][j][rr] + bs;
    }
  }
}

extern "C" void kernel_launch(void* const* d_in, const int* in_sizes, int n_in,
                              void* d_out, int out_size, void* d_ws, size_t ws_size,
                              hipStream_t stream) {
  (void)in_sizes; (void)n_in; (void)out_size; (void)ws_size;
  const float* x       = (const float*)d_in[0];
  const float* a_logit = (const float*)d_in[1];
  const float* U       = (const float*)d_in[2];
  const float* V       = (const float*)d_in[3];
  const float* W_in    = (const float*)d_in[4];
  const float* b_in    = (const float*)d_in[5];
  const float* W_gate  = (const float*)d_in[6];
  const float* b_gate  = (const float*)d_in[7];
  const float* W_out   = (const float*)d_in[8];
  const float* b_out   = (const float*)d_in[9];
  const float* W_skip  = (const float*)d_in[10];
  const float* b_skip  = (const float*)d_in[11];

  char* ws = (char*)d_ws;
  u16*   Xaug = (u16*)(ws + 0);            // 52,428,800 B
  u16*   Waug = (u16*)(ws + 52428800);     //  1,228,800 B
  u16*   WinG = (u16*)(ws + 53657600);     //     49,152 B
  float* gu_T = (float*)(ws + 53706752);   //  2,097,152 B
  float* Mw   = (float*)(ws + 55803904);   //      1,024 B
  float* MCw  = (float*)(ws + 55804928);   //      1,024 B
  float* bsum = (float*)(ws + 55805952);   //      3,072 B
  float* y    = (float*)d_out;

  hipLaunchKernelGGL(k_prep,    dim3(1),      dim3(256),  0, stream,
                     a_logit, U, V, b_out, b_skip, Mw, MCw, bsum);
  hipLaunchKernelGGL(k_weights, dim3(800),    dim3(256),  0, stream,
                     W_skip, W_out, W_in, W_gate, Waug, WinG);
  hipLaunchKernelGGL(k_gu,      dim3(256),    dim3(256),  0, stream,
                     x, WinG, b_in, b_gate, gu_T, Xaug);
  hipLaunchKernelGGL(k_scan,    dim3(BB),     dim3(1024), 0, stream,
                     gu_T, Mw, MCw, Xaug);
  hipLaunchKernelGGL(k_out,     dim3(256, 3), dim3(256),  0, stream,
                     Xaug, Waug, bsum, y, 0);
  hipLaunchKernelGGL(k_out,     dim3(256, 3), dim3(256),  0, stream,
                     Xaug, Waug, bsum, y, 3);
}